// Round 1
// baseline (367.610 us; speedup 1.0000x reference)
//
#include <hip/hip_runtime.h>

typedef unsigned short ushort_t;
typedef __attribute__((ext_vector_type(8))) __bf16 bf16x8;
typedef __attribute__((ext_vector_type(8))) unsigned short ushort8;
typedef __attribute__((ext_vector_type(4))) unsigned short ushort4v;
typedef __attribute__((ext_vector_type(4))) float floatx4;

__device__ inline unsigned short f2bf(float f) {
  union { float f; unsigned u; } x; x.f = f;
  return (unsigned short)((x.u + 0x7FFFu + ((x.u >> 16) & 1u)) >> 16);
}
__device__ inline float bf2f(unsigned short u) {
  union { unsigned u; float f; } x; x.u = ((unsigned)u) << 16;
  return x.f;
}

// ---------------- fp32 -> bf16 convert (vectorized, 8 elems/thread) ----------
__global__ void cvt_f32_bf16(const float* __restrict__ in, ushort_t* __restrict__ out, int n) {
  int i = (blockIdx.x * blockDim.x + threadIdx.x) * 8;
  if (i >= n) return;
  const float4* p = (const float4*)(in + i);
  float4 a = p[0], b = p[1];
  ushort8 o;
  o[0] = f2bf(a.x); o[1] = f2bf(a.y); o[2] = f2bf(a.z); o[3] = f2bf(a.w);
  o[4] = f2bf(b.x); o[5] = f2bf(b.y); o[6] = f2bf(b.z); o[7] = f2bf(b.w);
  *(ushort8*)(out + i) = o;
}

// ---------------- async global->LDS helper ----------------------------------
__device__ inline void gload_lds16(const void* g, void* l) {
  __builtin_amdgcn_global_load_lds(
      (const __attribute__((address_space(1))) unsigned int*)g,
      (__attribute__((address_space(3))) unsigned int*)l, 16, 0, 0);
}

__device__ inline void store_out(float* p, float v) { *p = v; }
__device__ inline void store_out(ushort_t* p, float v) { *p = f2bf(v); }

// ---------------- 128x128-tile NT GEMM: C = A[M,K] * B[N,K]^T + bias[N] -----
// K fixed at 1024. bf16 inputs, fp32 accumulate, OutT output (bf16 or fp32).
template <typename OutT>
__global__ void gemm_bt(const ushort_t* __restrict__ A, const ushort_t* __restrict__ Bm,
                        const float* __restrict__ bias, OutT* __restrict__ C,
                        int M, int N, long sA_, long sB_, long sBias_, long sC_) {
  const int K = 1024;
  int z = blockIdx.z;
  A += (long)z * sA_; Bm += (long)z * sB_; bias += (long)z * sBias_; C += (long)z * sC_;

  __shared__ ushort_t sA[128 * 32];
  __shared__ ushort_t sB[128 * 32];

  int t = threadIdx.x;
  int w = t >> 6, l = t & 63;
  int wy = w >> 1, wx = w & 1;
  int quad = l >> 4, m16 = l & 15;
  int mBase = blockIdx.y * 128, nBase = blockIdx.x * 128;

  // staging: wave w covers tile rows [w*32, w*32+32); 2 insts of 16 rows each.
  int sRow0 = w * 32 + (l >> 2);
  int sCol = (l & 3) * 8;
  const ushort_t* gA0 = A + (long)(mBase + sRow0) * K + sCol;
  const ushort_t* gA1 = gA0 + 16 * K;
  const ushort_t* gB0 = Bm + (long)(nBase + sRow0) * K + sCol;
  const ushort_t* gB1 = gB0 + 16 * K;
  ushort_t* lA0 = sA + (w * 2) * 512;
  ushort_t* lA1 = lA0 + 512;
  ushort_t* lB0 = sB + (w * 2) * 512;
  ushort_t* lB1 = lB0 + 512;

  int aOff = (wy * 64 + m16) * 32 + quad * 8;
  int bOff = (wx * 64 + m16) * 32 + quad * 8;

  floatx4 acc[4][4] = {};

  for (int kt = 0; kt < K; kt += 32) {
    __syncthreads();
    gload_lds16(gA0 + kt, lA0);
    gload_lds16(gA1 + kt, lA1);
    gload_lds16(gB0 + kt, lB0);
    gload_lds16(gB1 + kt, lB1);
    __syncthreads();
    bf16x8 af[4], bfr[4];
#pragma unroll
    for (int i = 0; i < 4; ++i) af[i] = *(const bf16x8*)(sA + aOff + i * 16 * 32);
#pragma unroll
    for (int i = 0; i < 4; ++i) bfr[i] = *(const bf16x8*)(sB + bOff + i * 16 * 32);
#pragma unroll
    for (int mi = 0; mi < 4; ++mi)
#pragma unroll
      for (int ni = 0; ni < 4; ++ni)
        acc[mi][ni] = __builtin_amdgcn_mfma_f32_16x16x32_bf16(af[mi], bfr[ni], acc[mi][ni], 0, 0, 0);
  }

#pragma unroll
  for (int ni = 0; ni < 4; ++ni) {
    int n = nBase + wx * 64 + ni * 16 + m16;
    float bb = bias[n];
#pragma unroll
    for (int mi = 0; mi < 4; ++mi) {
      int m0 = mBase + wy * 64 + mi * 16 + quad * 4;
      floatx4 v = acc[mi][ni];
#pragma unroll
      for (int r = 0; r < 4; ++r)
        store_out(&C[(long)(m0 + r) * N + n], v[r] + bb);
    }
  }
}

// ---------------- ktv partial: per (b,h,slice) accumulate K^T V -------------
// k,v: bf16 [16384,1024] rows b*4096+n, cols h*64+d. part: [64][8][64*64] fp32
__global__ void ktv_partial(const ushort_t* __restrict__ kbf, const ushort_t* __restrict__ vbf,
                            float* __restrict__ part) {
  int bh = blockIdx.x, sl = blockIdx.y;
  int b = bh >> 4, h = bh & 15;
  __shared__ ushort_t sK[32 * 64];
  __shared__ ushort_t sV[32 * 64];
  int t = threadIdx.x;
  int ty = t >> 4, tx = t & 15;
  float acc[4][4] = {};
  long base = ((long)(b * 4096 + sl * 512)) * 1024 + h * 64;
  for (int nc = 0; nc < 512; nc += 32) {
    __syncthreads();
    int nl = t >> 3, d0 = (t & 7) * 8;
    long g = base + (long)(nc + nl) * 1024 + d0;
    *(ushort8*)(sK + nl * 64 + d0) = *(const ushort8*)(kbf + g);
    *(ushort8*)(sV + nl * 64 + d0) = *(const ushort8*)(vbf + g);
    __syncthreads();
#pragma unroll 4
    for (int n = 0; n < 32; ++n) {
      ushort4v ku = *(const ushort4v*)(sK + n * 64 + ty * 4);
      ushort4v vu = *(const ushort4v*)(sV + n * 64 + tx * 4);
      float kf[4], vf[4];
#pragma unroll
      for (int i = 0; i < 4; ++i) { kf[i] = bf2f(ku[i]); vf[i] = bf2f(vu[i]); }
#pragma unroll
      for (int d = 0; d < 4; ++d)
#pragma unroll
        for (int e = 0; e < 4; ++e) acc[d][e] += kf[d] * vf[e];
    }
  }
  float* p = part + ((long)(bh * 8 + sl)) * 4096;
#pragma unroll
  for (int d = 0; d < 4; ++d)
#pragma unroll
    for (int e = 0; e < 4; ++e) p[(ty * 4 + d) * 64 + tx * 4 + e] = acc[d][e];
}

__global__ void ktv_reduce(const float* __restrict__ part, float* __restrict__ ktv) {
  int i = blockIdx.x * 256 + threadIdx.x;  // 64*4096 total
  int bh = i >> 12, de = i & 4095;
  float s = 0.f;
#pragma unroll
  for (int sl = 0; sl < 8; ++sl) s += part[((long)(bh * 8 + sl)) * 4096 + de];
  ktv[i] = s;
}

// ---------------- build W2T (bf16) and bias2 (fp32) -------------------------
// W2T[b][h*64+e][c] = scale * sum_d Wq[h*64+d][c] * ktv[b,h,d,e]
// bias2[b][h*64+e]  = scale * sum_d bq[h*64+d] * ktv[b,h,d,e]
__global__ void make_w2(const float* __restrict__ Wq, const float* __restrict__ bq,
                        const float* __restrict__ ktv, ushort_t* __restrict__ W2T,
                        float* __restrict__ bias2, float scale) {
  int bh = blockIdx.x, cq = blockIdx.y;
  int b = bh >> 4, h = bh & 15;
  __shared__ float sKTV[64 * 64];
  __shared__ float sW[64 * 64];
  int t = threadIdx.x;
  for (int i = t * 4; i < 4096; i += 1024)
    *(float4*)(sKTV + i) = *(const float4*)(ktv + (long)bh * 4096 + i);
  __syncthreads();
  if (cq == 0 && t < 64) {
    float s = 0.f;
    for (int d = 0; d < 64; ++d) s += bq[h * 64 + d] * sKTV[d * 64 + t];
    bias2[b * 1024 + h * 64 + t] = s * scale;
  }
  int e = t >> 2, c0 = (t & 3) * 16;
  for (int ct = cq * 256; ct < cq * 256 + 256; ct += 64) {
    __syncthreads();
    {
      int d = t >> 2, cc = (t & 3) * 16;
#pragma unroll
      for (int j = 0; j < 16; j += 4)
        *(float4*)(sW + d * 64 + cc + j) =
            *(const float4*)(Wq + (long)(h * 64 + d) * 1024 + ct + cc + j);
    }
    __syncthreads();
    float outv[16] = {};
    for (int d = 0; d < 64; ++d) {
      float kv = sKTV[d * 64 + e];
#pragma unroll
      for (int j = 0; j < 16; ++j) outv[j] += sW[d * 64 + c0 + j] * kv;
    }
    ushort8 o0, o1;
#pragma unroll
    for (int j = 0; j < 8; ++j) { o0[j] = f2bf(outv[j] * scale); o1[j] = f2bf(outv[8 + j] * scale); }
    ushort_t* dst = W2T + ((long)(b * 1024 + h * 64 + e)) * 1024 + ct + c0;
    *(ushort8*)dst = o0;
    *(ushort8*)(dst + 8) = o1;
  }
}

// ---------------- launch -----------------------------------------------------
extern "C" void kernel_launch(void* const* d_in, const int* in_sizes, int n_in,
                              void* d_out, int out_size, void* d_ws, size_t ws_size,
                              hipStream_t stream) {
  (void)in_sizes; (void)n_in; (void)out_size; (void)ws_size;
  const float* tens = (const float*)d_in[0];
  const float* Wq = (const float*)d_in[1];
  const float* bq = (const float*)d_in[2];
  const float* Wk = (const float*)d_in[3];
  const float* bk = (const float*)d_in[4];
  const float* Wv = (const float*)d_in[5];
  const float* bv = (const float*)d_in[6];
  float* out = (float*)d_out;

  char* w = (char*)d_ws;
  ushort_t* Xbf  = (ushort_t*)(w);                    // 33,554,432 B
  ushort_t* Kbf  = (ushort_t*)(w + 33554432);         // 33,554,432 B
  ushort_t* Vbf  = (ushort_t*)(w + 67108864);         // 33,554,432 B
  ushort_t* Wkbf = (ushort_t*)(w + 100663296);        //  2,097,152 B
  ushort_t* Wvbf = (ushort_t*)(w + 102760448);        //  2,097,152 B
  float*    part = (float*)(w + 104857600);           //  8,388,608 B
  float*    ktv  = (float*)(w + 113246208);           //  1,048,576 B
  ushort_t* W2T  = (ushort_t*)(w + 114294784);        //  8,388,608 B
  float*    bias2= (float*)(w + 122683392);           //     16,384 B

  const float scale = (1.0f / 8.0f) / 64.0f;  // 1/sqrt(DH)/sqrt(N)

  hipLaunchKernelGGL(cvt_f32_bf16, dim3(8192), dim3(256), 0, stream, tens, Xbf, 16777216);
  hipLaunchKernelGGL(cvt_f32_bf16, dim3(512), dim3(256), 0, stream, Wk, Wkbf, 1048576);
  hipLaunchKernelGGL(cvt_f32_bf16, dim3(512), dim3(256), 0, stream, Wv, Wvbf, 1048576);

  hipLaunchKernelGGL((gemm_bt<ushort_t>), dim3(8, 128, 1), dim3(256), 0, stream,
                     Xbf, Wkbf, bk, Kbf, 16384, 1024, 0L, 0L, 0L, 0L);
  hipLaunchKernelGGL((gemm_bt<ushort_t>), dim3(8, 128, 1), dim3(256), 0, stream,
                     Xbf, Wvbf, bv, Vbf, 16384, 1024, 0L, 0L, 0L, 0L);

  hipLaunchKernelGGL(ktv_partial, dim3(64, 8), dim3(256), 0, stream, Kbf, Vbf, part);
  hipLaunchKernelGGL(ktv_reduce, dim3(1024), dim3(256), 0, stream, part, ktv);
  hipLaunchKernelGGL(make_w2, dim3(64, 4), dim3(256), 0, stream, Wq, bq, ktv, W2T, bias2, scale);

  hipLaunchKernelGGL((gemm_bt<float>), dim3(8, 32, 4), dim3(256), 0, stream,
                     Xbf, W2T, bias2, out, 4096, 1024,
                     4194304L, 1048576L, 1024L, 4194304L);
}

// Round 2
// 309.392 us; speedup vs baseline: 1.1882x; 1.1882x over previous
//
#include <hip/hip_runtime.h>

typedef unsigned short ushort_t;
typedef __attribute__((ext_vector_type(8))) __bf16 bf16x8;
typedef __attribute__((ext_vector_type(8))) unsigned short ushort8;
typedef __attribute__((ext_vector_type(4))) float floatx4;

__device__ inline unsigned short f2bf(float f) {
  union { float f; unsigned u; } x; x.f = f;
  return (unsigned short)((x.u + 0x7FFFu + ((x.u >> 16) & 1u)) >> 16);
}

// ---------------- fp32 -> bf16 convert (vectorized, 8 elems/thread) ----------
__global__ void cvt_f32_bf16(const float* __restrict__ in, ushort_t* __restrict__ out, int n) {
  int i = (blockIdx.x * blockDim.x + threadIdx.x) * 8;
  if (i >= n) return;
  const float4* p = (const float4*)(in + i);
  float4 a = p[0], b = p[1];
  ushort8 o;
  o[0] = f2bf(a.x); o[1] = f2bf(a.y); o[2] = f2bf(a.z); o[3] = f2bf(a.w);
  o[4] = f2bf(b.x); o[5] = f2bf(b.y); o[6] = f2bf(b.z); o[7] = f2bf(b.w);
  *(ushort8*)(out + i) = o;
}

// ---------------- async global->LDS helper ----------------------------------
__device__ inline void gload_lds16(const void* g, void* l) {
  __builtin_amdgcn_global_load_lds(
      (const __attribute__((address_space(1))) unsigned int*)g,
      (__attribute__((address_space(3))) unsigned int*)l, 16, 0, 0);
}

__device__ inline void store_out(float* p, float v) { *p = v; }
__device__ inline void store_out(ushort_t* p, float v) { *p = f2bf(v); }

// ---------------- 128x128-tile NT GEMM: C = A[M,K] * B[N,K]^T + bias[N] -----
// K fixed at 1024. bf16 inputs, fp32 accumulate, OutT output (bf16 or fp32).
// LDS layout is XOR-swizzled in 16B blocks: phys[row][pb] = logical[row][pb ^ swz(row)],
// swz(r) = (r ^ (r>>2)) & 3. Applied on the GLOBAL address side of global_load_lds
// (LDS dest must be lane-contiguous). Kills the 8-way quarter-wave bank conflict.
template <typename OutT>
__global__ void gemm_bt(const ushort_t* __restrict__ A, const ushort_t* __restrict__ Bm,
                        const float* __restrict__ bias, OutT* __restrict__ C,
                        int M, int N, long sA_, long sB_, long sBias_, long sC_) {
  const int K = 1024;

  // XCD-aware remap: dispatch round-robins flat block id over 8 XCDs; give each
  // XCD a contiguous run of (x,y,z) tiles so A-tiles are fetched once per XCD L2.
  int gx = gridDim.x, gxy = gridDim.x * gridDim.y;
  int flat = blockIdx.x + gx * blockIdx.y + gxy * blockIdx.z;
  int total = gxy * gridDim.z;
  int per = total >> 3;
  int nf = (flat & 7) * per + (flat >> 3);
  int bz = nf / gxy; int rem = nf - bz * gxy;
  int by = rem / gx; int bx = rem - by * gx;

  A += (long)bz * sA_; Bm += (long)bz * sB_; bias += (long)bz * sBias_; C += (long)bz * sC_;

  __shared__ ushort_t sA[128 * 32];
  __shared__ ushort_t sB[128 * 32];

  int t = threadIdx.x;
  int w = t >> 6, l = t & 63;
  int wy = w >> 1, wx = w & 1;
  int quad = l >> 4, m16 = l & 15;
  int mBase = by * 128, nBase = bx * 128;

  // staging: wave w covers tile rows [w*32, w*32+32); 2 insts of 16 rows each.
  int r = l >> 2, pb = l & 3;
  int swzS = (r ^ (r >> 2)) & 3;
  int sRow0 = w * 32 + r;
  int sCol = (pb ^ swzS) * 8;  // swizzled 16B block within the 64B row
  const ushort_t* gA0 = A + (long)(mBase + sRow0) * K + sCol;
  const ushort_t* gA1 = gA0 + 16 * K;
  const ushort_t* gB0 = Bm + (long)(nBase + sRow0) * K + sCol;
  const ushort_t* gB1 = gB0 + 16 * K;
  ushort_t* lA0 = sA + (w * 2) * 512;
  ushort_t* lA1 = lA0 + 512;
  ushort_t* lB0 = sB + (w * 2) * 512;
  ushort_t* lB1 = lB0 + 512;

  int swzR = (m16 ^ (m16 >> 2)) & 3;
  int aOff = (wy * 64 + m16) * 32 + (quad ^ swzR) * 8;
  int bOff = (wx * 64 + m16) * 32 + (quad ^ swzR) * 8;

  floatx4 acc[4][4] = {};

  for (int kt = 0; kt < K; kt += 32) {
    __syncthreads();
    gload_lds16(gA0 + kt, lA0);
    gload_lds16(gA1 + kt, lA1);
    gload_lds16(gB0 + kt, lB0);
    gload_lds16(gB1 + kt, lB1);
    __syncthreads();
    bf16x8 af[4], bfr[4];
#pragma unroll
    for (int i = 0; i < 4; ++i) af[i] = *(const bf16x8*)(sA + aOff + i * 16 * 32);
#pragma unroll
    for (int i = 0; i < 4; ++i) bfr[i] = *(const bf16x8*)(sB + bOff + i * 16 * 32);
#pragma unroll
    for (int mi = 0; mi < 4; ++mi)
#pragma unroll
      for (int ni = 0; ni < 4; ++ni)
        acc[mi][ni] = __builtin_amdgcn_mfma_f32_16x16x32_bf16(af[mi], bfr[ni], acc[mi][ni], 0, 0, 0);
  }

#pragma unroll
  for (int ni = 0; ni < 4; ++ni) {
    int n = nBase + wx * 64 + ni * 16 + m16;
    float bb = bias[n];
#pragma unroll
    for (int mi = 0; mi < 4; ++mi) {
      int m0 = mBase + wy * 64 + mi * 16 + quad * 4;
      floatx4 v = acc[mi][ni];
#pragma unroll
      for (int rr = 0; rr < 4; ++rr)
        store_out(&C[(long)(m0 + rr) * N + n], v[rr] + bb);
    }
  }
}

// ---------------- ktv via MFMA: per (b,h,slice) partial K^T V ----------------
// K,V bf16 [16384,1024] rows b*4096+n, cols h*64+d. part: [64][8][64*64] fp32.
// Transpose-stage 32n x 64d tiles into LDS [d][n] (stride 40 shorts: 16B-aligned
// rows, conflict-free b128 frag reads), then 16x16x32 bf16 MFMA over n.
__global__ void ktv_mfma(const ushort_t* __restrict__ Kb, const ushort_t* __restrict__ Vb,
                         float* __restrict__ part) {
  int bh = blockIdx.x, sl = blockIdx.y;  // 64 x 8
  int b = bh >> 4, h = bh & 15;
  __shared__ ushort_t sKT[64 * 40];
  __shared__ ushort_t sVT[64 * 40];
  int t = threadIdx.x;
  int w = t >> 6, l = t & 63;
  int quad = l >> 4, m16 = l & 15;
  int nr = t & 31, d0 = (t >> 5) * 8;
  long base = ((long)(b * 4096 + sl * 512)) * 1024 + h * 64;
  floatx4 acc[4] = {};
  for (int nc = 0; nc < 512; nc += 32) {
    __syncthreads();
    ushort8 kv = *(const ushort8*)(Kb + base + (long)(nc + nr) * 1024 + d0);
    ushort8 vv = *(const ushort8*)(Vb + base + (long)(nc + nr) * 1024 + d0);
#pragma unroll
    for (int i = 0; i < 8; ++i) {
      sKT[(d0 + i) * 40 + nr] = kv[i];
      sVT[(d0 + i) * 40 + nr] = vv[i];
    }
    __syncthreads();
    bf16x8 af = *(const bf16x8*)(sKT + (w * 16 + m16) * 40 + quad * 8);
#pragma unroll
    for (int j = 0; j < 4; ++j) {
      bf16x8 bf = *(const bf16x8*)(sVT + (j * 16 + m16) * 40 + quad * 8);
      acc[j] = __builtin_amdgcn_mfma_f32_16x16x32_bf16(af, bf, acc[j], 0, 0, 0);
    }
  }
  float* p = part + ((long)(bh * 8 + sl)) * 4096;
#pragma unroll
  for (int j = 0; j < 4; ++j)
#pragma unroll
    for (int rr = 0; rr < 4; ++rr)
      p[(w * 16 + quad * 4 + rr) * 64 + j * 16 + m16] = acc[j][rr];
}

__global__ void ktv_reduce(const float* __restrict__ part, float* __restrict__ ktv) {
  int i = blockIdx.x * 256 + threadIdx.x;  // 64*4096 total
  int bh = i >> 12, de = i & 4095;
  float s = 0.f;
#pragma unroll
  for (int sl = 0; sl < 8; ++sl) s += part[((long)(bh * 8 + sl)) * 4096 + de];
  ktv[i] = s;
}

// ---------------- build W2T (bf16) and bias2 (fp32) -------------------------
// W2T[b][h*64+e][c] = scale * sum_d Wq[h*64+d][c] * ktv[b,h,d,e]
// bias2[b][h*64+e]  = scale * sum_d bq[h*64+d] * ktv[b,h,d,e]
__global__ void make_w2(const float* __restrict__ Wq, const float* __restrict__ bq,
                        const float* __restrict__ ktv, ushort_t* __restrict__ W2T,
                        float* __restrict__ bias2, float scale) {
  int bh = blockIdx.x, cq = blockIdx.y;
  int b = bh >> 4, h = bh & 15;
  __shared__ float sKTV[64 * 64];
  __shared__ float sW[64 * 64];
  int t = threadIdx.x;
  for (int i = t * 4; i < 4096; i += 1024)
    *(float4*)(sKTV + i) = *(const float4*)(ktv + (long)bh * 4096 + i);
  __syncthreads();
  if (cq == 0 && t < 64) {
    float s = 0.f;
    for (int d = 0; d < 64; ++d) s += bq[h * 64 + d] * sKTV[d * 64 + t];
    bias2[b * 1024 + h * 64 + t] = s * scale;
  }
  int e = t >> 2, c0 = (t & 3) * 16;
  for (int ct = cq * 256; ct < cq * 256 + 256; ct += 64) {
    __syncthreads();
    {
      int d = t >> 2, cc = (t & 3) * 16;
#pragma unroll
      for (int j = 0; j < 16; j += 4)
        *(float4*)(sW + d * 64 + cc + j) =
            *(const float4*)(Wq + (long)(h * 64 + d) * 1024 + ct + cc + j);
    }
    __syncthreads();
    float outv[16] = {};
    for (int d = 0; d < 64; ++d) {
      float kv = sKTV[d * 64 + e];
#pragma unroll
      for (int j = 0; j < 16; ++j) outv[j] += sW[d * 64 + c0 + j] * kv;
    }
    ushort8 o0, o1;
#pragma unroll
    for (int j = 0; j < 8; ++j) { o0[j] = f2bf(outv[j] * scale); o1[j] = f2bf(outv[8 + j] * scale); }
    ushort_t* dst = W2T + ((long)(b * 1024 + h * 64 + e)) * 1024 + ct + c0;
    *(ushort8*)dst = o0;
    *(ushort8*)(dst + 8) = o1;
  }
}

// ---------------- launch -----------------------------------------------------
extern "C" void kernel_launch(void* const* d_in, const int* in_sizes, int n_in,
                              void* d_out, int out_size, void* d_ws, size_t ws_size,
                              hipStream_t stream) {
  (void)in_sizes; (void)n_in; (void)out_size; (void)ws_size;
  const float* tens = (const float*)d_in[0];
  const float* Wq = (const float*)d_in[1];
  const float* bq = (const float*)d_in[2];
  const float* Wk = (const float*)d_in[3];
  const float* bk = (const float*)d_in[4];
  const float* Wv = (const float*)d_in[5];
  const float* bv = (const float*)d_in[6];
  float* out = (float*)d_out;

  char* w = (char*)d_ws;
  ushort_t* Xbf  = (ushort_t*)(w);                    // 33,554,432 B
  ushort_t* Kbf  = (ushort_t*)(w + 33554432);         // 33,554,432 B
  ushort_t* Vbf  = (ushort_t*)(w + 67108864);         // 33,554,432 B
  ushort_t* Wkbf = (ushort_t*)(w + 100663296);        //  2,097,152 B
  ushort_t* Wvbf = (ushort_t*)(w + 102760448);        //  2,097,152 B
  float*    part = (float*)(w + 104857600);           //  8,388,608 B
  float*    ktv  = (float*)(w + 113246208);           //  1,048,576 B
  ushort_t* W2T  = (ushort_t*)(w + 114294784);        //  8,388,608 B
  float*    bias2= (float*)(w + 122683392);           //     16,384 B

  const float scale = (1.0f / 8.0f) / 64.0f;  // 1/sqrt(DH)/sqrt(N)

  hipLaunchKernelGGL(cvt_f32_bf16, dim3(8192), dim3(256), 0, stream, tens, Xbf, 16777216);
  hipLaunchKernelGGL(cvt_f32_bf16, dim3(512), dim3(256), 0, stream, Wk, Wkbf, 1048576);
  hipLaunchKernelGGL(cvt_f32_bf16, dim3(512), dim3(256), 0, stream, Wv, Wvbf, 1048576);

  hipLaunchKernelGGL((gemm_bt<ushort_t>), dim3(8, 128, 1), dim3(256), 0, stream,
                     Xbf, Wkbf, bk, Kbf, 16384, 1024, 0L, 0L, 0L, 0L);
  hipLaunchKernelGGL((gemm_bt<ushort_t>), dim3(8, 128, 1), dim3(256), 0, stream,
                     Xbf, Wvbf, bv, Vbf, 16384, 1024, 0L, 0L, 0L, 0L);

  hipLaunchKernelGGL(ktv_mfma, dim3(64, 8), dim3(256), 0, stream, Kbf, Vbf, part);
  hipLaunchKernelGGL(ktv_reduce, dim3(1024), dim3(256), 0, stream, part, ktv);
  hipLaunchKernelGGL(make_w2, dim3(64, 4), dim3(256), 0, stream, Wq, bq, ktv, W2T, bias2, scale);

  hipLaunchKernelGGL((gemm_bt<float>), dim3(8, 32, 4), dim3(256), 0, stream,
                     Xbf, W2T, bias2, out, 4096, 1024,
                     4194304L, 1048576L, 1024L, 4194304L);
}